// Round 1
// 698.596 us; speedup vs baseline: 1.9439x; 1.9439x over previous
//
#include <hip/hip_runtime.h>
#include <cstdint>
#include <cstddef>
#include <cstdio>

#define DI __device__ __forceinline__

typedef __attribute__((ext_vector_type(4))) float f32x4;
typedef __attribute__((ext_vector_type(8))) short bf16x8;

static constexpr int TOK  = 2048;   // B*T
static constexpr int CDIM = 1024;
static constexpr int IDIM = 4096;
static constexpr int RHID = 256;    // router hidden
static constexpr int RK   = 4096;   // router split-K: [xhi|xhi|xlo|xlo]·[whi|wlo|whi|wlo]
static constexpr int PAIR_CAP = 2048 + 4096 + 8 * 128;  // shared + routed + pad = 7168

DI float bf2f(unsigned short u) {
  unsigned int v = ((unsigned int)u) << 16;
  float f; __builtin_memcpy(&f, &v, sizeof(f));
  return f;
}
DI unsigned short f2bf(float f) {
  unsigned int u; __builtin_memcpy(&u, &f, sizeof(u));
  u += 0x7fffu + ((u >> 16) & 1u);   // RNE
  return (unsigned short)(u >> 16);
}

// async global->LDS DMA, 16B per lane. LDS dest must be wave-uniform base + lane*16.
DI void gload16(const unsigned short* g, unsigned short* l) {
  unsigned short* gm = const_cast<unsigned short*>(g);
  __builtin_amdgcn_global_load_lds(
      (__attribute__((address_space(1))) void*)gm,
      (__attribute__((address_space(3))) void*)l, 16, 0, 0);
}

// ---- x (fp32) -> xb (bf16), xcat (bf16 [2048][4096] = [hi|hi|lo|lo]) ----
__global__ void cvt_x_k(const float* __restrict__ x, unsigned short* __restrict__ xb,
                        unsigned short* __restrict__ xcat) {
  const int i = (blockIdx.x * 256 + threadIdx.x) * 4;   // over 2048*1024 elems
  const float4 v = *(const float4*)(x + i);
  unsigned short hi[4], lo[4];
  const float vf[4] = {v.x, v.y, v.z, v.w};
#pragma unroll
  for (int j = 0; j < 4; ++j) {
    hi[j] = f2bf(vf[j]);
    lo[j] = f2bf(vf[j] - bf2f(hi[j]));
  }
  const int row = i >> 10, col = i & 1023;
  *(uint2*)(xb + (size_t)row * CDIM + col) = *(const uint2*)hi;
  unsigned short* xr = xcat + (size_t)row * RK;
  *(uint2*)(xr + col)        = *(const uint2*)hi;
  *(uint2*)(xr + col + 1024) = *(const uint2*)hi;
  *(uint2*)(xr + col + 2048) = *(const uint2*)lo;
  *(uint2*)(xr + col + 3072) = *(const uint2*)lo;
}

// ---- fp32 src[R][Cc] -> bf16 dst[Cc][R] (transpose + downcast), batched z ----
__global__ void transpose_f2b_k(const float* __restrict__ src, unsigned short* __restrict__ dst,
                                int R, int Cc) {
  __shared__ float tile[64][65];
  src += (size_t)blockIdx.z * R * Cc;
  dst += (size_t)blockIdx.z * R * Cc;
  const int c0 = blockIdx.x * 64, r0 = blockIdx.y * 64;
  const int t = threadIdx.x;
  const int tr = t >> 4, tc = (t & 15) * 4;
#pragma unroll
  for (int it = 0; it < 4; ++it) {
    const int r = tr + it * 16;
    const float4 v = *(const float4*)(src + (size_t)(r0 + r) * Cc + c0 + tc);
    tile[r][tc] = v.x; tile[r][tc + 1] = v.y; tile[r][tc + 2] = v.z; tile[r][tc + 3] = v.w;
  }
  __syncthreads();
  const int j0 = (t & 7) * 8;
#pragma unroll
  for (int it = 0; it < 2; ++it) {
    const int cl = (t >> 3) + it * 32;
    unsigned short tmp[8];
#pragma unroll
    for (int j = 0; j < 8; ++j) tmp[j] = f2bf(tile[j0 + j][cl]);
    *(uint4*)(dst + (size_t)(c0 + cl) * R + r0 + j0) = *(const uint4*)tmp;
  }
}

// ---- rw1 fp32 [1024][256] -> wcat bf16 [256][4096] = [whi|wlo|whi|wlo] ----
__global__ void router_w_prep(const float* __restrict__ src, unsigned short* __restrict__ dst) {
  __shared__ float tile[64][65];
  const int Cc = RHID;
  const int c0 = blockIdx.x * 64, r0 = blockIdx.y * 64;
  const int t = threadIdx.x;
  const int tr = t >> 4, tc = (t & 15) * 4;
#pragma unroll
  for (int it = 0; it < 4; ++it) {
    const int r = tr + it * 16;
    const float4 v = *(const float4*)(src + (size_t)(r0 + r) * Cc + c0 + tc);
    tile[r][tc] = v.x; tile[r][tc + 1] = v.y; tile[r][tc + 2] = v.z; tile[r][tc + 3] = v.w;
  }
  __syncthreads();
  const int j0 = (t & 7) * 8;
#pragma unroll
  for (int it = 0; it < 2; ++it) {
    const int cl = (t >> 3) + it * 32;
    unsigned short hi[8], lo[8];
#pragma unroll
    for (int j = 0; j < 8; ++j) {
      const float v = tile[j0 + j][cl];
      hi[j] = f2bf(v);
      lo[j] = f2bf(v - bf2f(hi[j]));
    }
    unsigned short* dr = dst + (size_t)(c0 + cl) * RK + r0 + j0;
    *(uint4*)(dr)        = *(const uint4*)hi;
    *(uint4*)(dr + 1024) = *(const uint4*)lo;
    *(uint4*)(dr + 2048) = *(const uint4*)hi;
    *(uint4*)(dr + 3072) = *(const uint4*)lo;
  }
}

__global__ void zero_f32(float4* __restrict__ p) {
  p[(size_t)blockIdx.x * 256 + threadIdx.x] = make_float4(0.f, 0.f, 0.f, 0.f);
}

// ---------------- small setup kernels ----------------
// meta: [0..7] counts, [8..15] fill, [16..23] row offsets, [32..39] tiles
__global__ void init_meta(int* __restrict__ meta, int* __restrict__ pair_token) {
  const int i = blockIdx.x * 256 + threadIdx.x;
  if (i < 64) meta[i] = 0;
  if (i < PAIR_CAP) pair_token[i] = (i < TOK) ? i : 0;
}

__global__ void router_finish(const float* __restrict__ rh,
                              const float* __restrict__ rw2,
                              const float* __restrict__ rb2,
                              int* __restrict__ tok_e, float* __restrict__ tok_w,
                              int* __restrict__ meta) {
  const int wave = threadIdx.x >> 6, lane = threadIdx.x & 63;
  const int t = blockIdx.x * 4 + wave;
  float a[8] = {0, 0, 0, 0, 0, 0, 0, 0};
  const float* hp = rh + (size_t)t * RHID;
#pragma unroll
  for (int it = 0; it < 4; ++it) {
    const int j = it * 64 + lane;
    const float hv = fmaxf(hp[j], 0.0f);          // relu moved here (gemm is split-K linear)
    const float4 wa = *(const float4*)(rw2 + (size_t)j * 8);
    const float4 wb = *(const float4*)(rw2 + (size_t)j * 8 + 4);
    a[0] += hv * wa.x; a[1] += hv * wa.y; a[2] += hv * wa.z; a[3] += hv * wa.w;
    a[4] += hv * wb.x; a[5] += hv * wb.y; a[6] += hv * wb.z; a[7] += hv * wb.w;
  }
#pragma unroll
  for (int off = 32; off > 0; off >>= 1)
#pragma unroll
    for (int e = 0; e < 8; ++e) a[e] += __shfl_down(a[e], off);
  if (lane == 0) {
    float lg[8], mx = -1e30f;
#pragma unroll
    for (int e = 0; e < 8; ++e) { lg[e] = a[e] + rb2[e]; mx = fmaxf(mx, lg[e]); }
    float s = 0.f;
#pragma unroll
    for (int e = 0; e < 8; ++e) { lg[e] = __expf(lg[e] - mx); s += lg[e]; }
    const float inv = 1.f / s;
#pragma unroll
    for (int e = 0; e < 8; ++e) lg[e] *= inv;
    int e1 = 0; float g1 = lg[0];
#pragma unroll
    for (int e = 1; e < 8; ++e) if (lg[e] > g1) { g1 = lg[e]; e1 = e; }
    int e2 = -1; float g2 = -1e30f;
#pragma unroll
    for (int e = 0; e < 8; ++e) if (e != e1 && lg[e] > g2) { g2 = lg[e]; e2 = e; }
    const float eb = __expf((g2 - g1) * 0.5f);
    const float w1 = 1.f / (1.f + eb), w2 = eb / (1.f + eb);
    tok_e[2 * t] = e1; tok_e[2 * t + 1] = e2;
    tok_w[2 * t] = w1; tok_w[2 * t + 1] = w2;
    atomicAdd(&meta[e1], 1); atomicAdd(&meta[e2], 1);
  }
}

__global__ void compute_offsets(int* __restrict__ meta) {
  if (threadIdx.x == 0) {
    int o = TOK;
    for (int e = 0; e < 8; ++e) {
      meta[16 + e] = o;
      const int tl = (meta[e] + 127) >> 7;
      meta[32 + e] = tl;
      o += tl << 7;
    }
  }
}

__global__ void scatter_pairs(const int* __restrict__ tok_e, int* __restrict__ meta,
                              int* __restrict__ pair_token, int* __restrict__ pair_pos) {
  const int t = blockIdx.x * 256 + threadIdx.x;
#pragma unroll
  for (int k = 0; k < 2; ++k) {
    const int e = tok_e[2 * t + k];
    const int pos = meta[16 + e] + atomicAdd(&meta[8 + e], 1);
    pair_token[pos] = t;
    pair_pos[2 * t + k] = pos;
  }
}

// ---------------- 128x128 MFMA GEMM, C = act(A @ Bt^T + bias) ----------------
// MODE 0: plain (router). MODE 1: MoE gather x->h. MODE 2: MoE h->op.
// Bt is [N][K] row-major bf16. zz==8 selects the shared expert. Biases fp32.
// SPLIT>1: split-K with fp32 atomicAdd into pre-zeroed Cout (ACT must be 0);
//   MODE 0: blockIdx.z = split index; MODE 2: blockIdx.z = expert + 9*split.
// K-loop: double-buffered LDS + global_load_lds DMA (2-phase: issue next tile,
// compute current, one __syncthreads whose vmcnt(0) drain completes the stage).
template <int MODE, int ACT, bool OUTF32, int SPLIT>
__global__ __launch_bounds__(256) void gemm128(
    const unsigned short* __restrict__ A,
    const unsigned short* __restrict__ BtE, const unsigned short* __restrict__ BtS,
    const float* __restrict__ biasE, const float* __restrict__ biasS,
    void* __restrict__ Cout,
    const int* __restrict__ meta, const int* __restrict__ pair_token,
    int N, int K) {
  __shared__ unsigned short Alds[2][128 * 32];
  __shared__ unsigned short Blds[2][128 * 32];

  const int tid = threadIdx.x, wave = tid >> 6, lane = tid & 63;

  int ks = 0, zz = blockIdx.z;
  if (MODE == 0) {
    ks = zz;
  } else if (SPLIT > 1) {
    ks = zz / 9; zz -= ks * 9;
  }

  const unsigned short* Bt;
  const float* bias;
  int row0;
  if (MODE == 0) {
    row0 = blockIdx.y * 128; Bt = BtE; bias = biasE;
  } else {
    if (zz < 8) {
      if ((int)blockIdx.y >= meta[32 + zz]) return;
      row0 = meta[16 + zz] + blockIdx.y * 128;
      Bt = BtE + (size_t)zz * N * K;
      bias = biasE + zz * N;
    } else {
      row0 = blockIdx.y * 128;
      Bt = BtS; bias = biasS;
    }
  }
  const int n0 = blockIdx.x * 128;
  const int Kc = K / SPLIT;
  const size_t kbase = (size_t)ks * Kc;

  // chunk q (0..511): row m=q>>2; LDS slot q&3 (linear in lane order -> DMA-compatible)
  // holds global data chunk c = (q&3) ^ ((m>>1)&3)  [XOR-swizzled SOURCE, rule #21]
  const unsigned short* aSrc[2];
  const unsigned short* bSrc[2];
  int ldsOff[2];
#pragma unroll
  for (int i = 0; i < 2; ++i) {
    const int q = i * 256 + tid;
    const int m = q >> 2;
    const int c = (q & 3) ^ ((m >> 1) & 3);
    const size_t arow = (MODE == 1) ? (size_t)pair_token[row0 + m] : (size_t)(row0 + m);
    aSrc[i] = A + arow * K + kbase + c * 8;
    bSrc[i] = Bt + (size_t)(n0 + m) * K + kbase + c * 8;
    ldsOff[i] = q * 8;
  }

  const int wr = wave >> 1, wc = wave & 1;
  int aOff[4], bOff[4];
#pragma unroll
  for (int t = 0; t < 4; ++t) {
    const int ar = wr * 64 + t * 16 + (lane & 15);
    aOff[t] = (ar * 4 + ((lane >> 4) ^ ((ar >> 1) & 3))) * 8;
    const int br = wc * 64 + t * 16 + (lane & 15);
    bOff[t] = (br * 4 + ((lane >> 4) ^ ((br >> 1) & 3))) * 8;
  }

  f32x4 acc[4][4] = {};
  const int kIters = Kc >> 5;

  // prologue: stage K-step 0 into buffer 0
#pragma unroll
  for (int i = 0; i < 2; ++i) {
    gload16(aSrc[i], &Alds[0][ldsOff[i]]);
    gload16(bSrc[i], &Blds[0][ldsOff[i]]);
  }
  __syncthreads();   // vmcnt(0) drain: buf0 staged everywhere

  for (int kk = 0; kk < kIters; ++kk) {
    const int cur = kk & 1, nxt = cur ^ 1;
    if (kk + 1 < kIters) {          // issue next-tile DMA; lands under this tile's compute
      const int ko = (kk + 1) * 32;
#pragma unroll
      for (int i = 0; i < 2; ++i) {
        gload16(aSrc[i] + ko, &Alds[nxt][ldsOff[i]]);
        gload16(bSrc[i] + ko, &Blds[nxt][ldsOff[i]]);
      }
    }
    bf16x8 af[4], bfr[4];
#pragma unroll
    for (int t = 0; t < 4; ++t) {
      af[t]  = *(const bf16x8*)(&Alds[cur][aOff[t]]);
      bfr[t] = *(const bf16x8*)(&Blds[cur][bOff[t]]);
    }
#pragma unroll
    for (int mt = 0; mt < 4; ++mt)
#pragma unroll
      for (int nt = 0; nt < 4; ++nt)
        acc[mt][nt] = __builtin_amdgcn_mfma_f32_16x16x32_bf16(af[mt], bfr[nt], acc[mt][nt], 0, 0, 0);
    __syncthreads();   // vmcnt(0)+barrier: next buf staged, all reads of cur done
  }

  float bv[4];
  const bool addb = (SPLIT == 1) || (ks == 0);
#pragma unroll
  for (int nt = 0; nt < 4; ++nt)
    bv[nt] = addb ? bias[n0 + wc * 64 + nt * 16 + (lane & 15)] : 0.0f;

  // C/D layout: col = lane&15, row = (lane>>4)*4 + reg  [m89-verified]
  const int rb = row0 + wr * 64 + ((lane >> 4) * 4);
  const int cb = n0 + wc * 64 + (lane & 15);
#pragma unroll
  for (int mt = 0; mt < 4; ++mt)
#pragma unroll
    for (int nt = 0; nt < 4; ++nt)
#pragma unroll
      for (int r = 0; r < 4; ++r) {
        float v = acc[mt][nt][r] + bv[nt];
        if (ACT == 1) v = fmaxf(v, 0.0f);
        if (ACT == 2) v = v / (1.0f + __expf(-v));   // silu
        const size_t idx = (size_t)(rb + mt * 16 + r) * (size_t)N + (size_t)(cb + nt * 16);
        if (SPLIT > 1)   atomicAdd((float*)Cout + idx, v);
        else if (OUTF32) ((float*)Cout)[idx] = v;
        else             ((unsigned short*)Cout)[idx] = f2bf(v);
      }
}

// ---------------- final combine: y = shared + w0*pair0 + w1*pair1 (fp32 out) ----------------
__global__ void combine_out(const float* __restrict__ op, const int* __restrict__ pair_pos,
                            const float* __restrict__ tok_w, float* __restrict__ y) {
  const int t = blockIdx.x;
  const int c = threadIdx.x * 4;
  const int p0 = pair_pos[2 * t], p1 = pair_pos[2 * t + 1];
  const float w0 = tok_w[2 * t], w1 = tok_w[2 * t + 1];
  const float4 vs = *(const float4*)(op + (size_t)t  * CDIM + c);
  const float4 va = *(const float4*)(op + (size_t)p0 * CDIM + c);
  const float4 vb = *(const float4*)(op + (size_t)p1 * CDIM + c);
  float4 o;
  o.x = vs.x + w0 * va.x + w1 * vb.x;
  o.y = vs.y + w0 * va.y + w1 * vb.y;
  o.z = vs.z + w0 * va.z + w1 * vb.z;
  o.w = vs.w + w0 * va.w + w1 * vb.w;
  *(float4*)(y + (size_t)t * CDIM + c) = o;
}

extern "C" void kernel_launch(void* const* d_in, const int* in_sizes, int n_in,
                              void* d_out, int out_size, void* d_ws, size_t ws_size,
                              hipStream_t stream) {
  const float* x   = (const float*)d_in[0];
  const float* rw1 = (const float*)d_in[1];
  const float* rb1 = (const float*)d_in[2];
  const float* rw2 = (const float*)d_in[3];
  const float* rb2 = (const float*)d_in[4];
  const float* ew1 = (const float*)d_in[5];
  const float* eb1 = (const float*)d_in[6];
  const float* ew2 = (const float*)d_in[7];
  const float* eb2 = (const float*)d_in[8];
  const float* sw1 = (const float*)d_in[9];
  const float* sb1 = (const float*)d_in[10];
  const float* sw2 = (const float*)d_in[11];
  const float* sb2 = (const float*)d_in[12];

  char* w = (char*)d_ws;
  auto alloc = [&](size_t bytes) {
    char* p = w; w += (bytes + 255) & ~(size_t)255; return p;
  };
  unsigned short* ew1T = (unsigned short*)alloc(8ull * IDIM * CDIM * 2);   // [e][I][C] bf16
  unsigned short* ew2T = (unsigned short*)alloc(8ull * CDIM * IDIM * 2);   // [e][C][I] bf16
  unsigned short* sw1T = (unsigned short*)alloc((size_t)IDIM * CDIM * 2);
  unsigned short* sw2T = (unsigned short*)alloc((size_t)CDIM * IDIM * 2);
  unsigned short* h    = (unsigned short*)alloc((size_t)PAIR_CAP * IDIM * 2);
  float* op            = (float*)alloc((size_t)PAIR_CAP * CDIM * 4);
  float* tok_w         = (float*)alloc(2 * TOK * 4);
  int*   tok_e         = (int*)alloc(2 * TOK * 4);
  int*   meta          = (int*)alloc(64 * 4);
  int*   pair_token    = (int*)alloc(PAIR_CAP * 4);
  int*   pair_pos      = (int*)alloc(2 * TOK * 4);
  const size_t need = (size_t)(w - (char*)d_ws);
  if (need > ws_size) {
    fprintf(stderr, "kernel_launch: ws too small: need %zu have %zu\n", need, ws_size);
    return;
  }
  // Aliased scratch (dead before their hosts are written, stream-ordered):
  //   xcat (16.8 MB) lives in h (58.7 MB) — h written by GEMM1, after router consumes xcat
  //   wcat @ op+0 (2.1 MB), rh @ op+4MB (2.1 MB), xb @ op+8MB (4.2 MB) — op zeroed+written
  //   only after GEMM1 (which is the last consumer of xb)
  unsigned short* xcat = (unsigned short*)h;
  unsigned short* wcat = (unsigned short*)((char*)op);
  float*          rh   = (float*)((char*)op + (4ull << 20));
  unsigned short* xb   = (unsigned short*)((char*)op + (8ull << 20));

  // fp32 -> bf16 conversions (+ transposes): weights and activations
  cvt_x_k<<<TOK * CDIM / 1024, 256, 0, stream>>>(x, xb, xcat);
  router_w_prep<<<dim3(RHID / 64, CDIM / 64, 1), 256, 0, stream>>>(rw1, wcat);
  transpose_f2b_k<<<dim3(IDIM / 64, CDIM / 64, 8), 256, 0, stream>>>(ew1, ew1T, CDIM, IDIM);
  transpose_f2b_k<<<dim3(CDIM / 64, IDIM / 64, 8), 256, 0, stream>>>(ew2, ew2T, IDIM, CDIM);
  transpose_f2b_k<<<dim3(IDIM / 64, CDIM / 64, 1), 256, 0, stream>>>(sw1, sw1T, CDIM, IDIM);
  transpose_f2b_k<<<dim3(CDIM / 64, IDIM / 64, 1), 256, 0, stream>>>(sw2, sw2T, IDIM, CDIM);

  init_meta<<<PAIR_CAP / 256, 256, 0, stream>>>(meta, pair_token);

  // router hidden: rh = x @ rw1 + rb1 (linear; relu applied in router_finish)
  // split-K=8 over RK=4096 -> 256 blocks, atomicAdd into zeroed rh
  zero_f32<<<TOK * RHID / 1024, 256, 0, stream>>>((float4*)rh);
  gemm128<0, 0, true, 8><<<dim3(RHID / 128, TOK / 128, 8), 256, 0, stream>>>(
      xcat, wcat, nullptr, rb1, nullptr, rh, nullptr, nullptr, RHID, RK);
  router_finish<<<TOK / 4, 256, 0, stream>>>(rh, rw2, rb2, tok_e, tok_w, meta);
  compute_offsets<<<1, 64, 0, stream>>>(meta);
  scatter_pairs<<<TOK / 256, 256, 0, stream>>>(tok_e, meta, pair_token, pair_pos);

  // expert FFN (zz = 0..7 routed experts, zz = 8 shared expert over all tokens)
  gemm128<1, 2, false, 1><<<dim3(IDIM / 128, 16, 9), 256, 0, stream>>>(
      xb, ew1T, sw1T, eb1, sb1, h, meta, pair_token, IDIM, CDIM);
  // GEMM2: split-K=2 over IDIM=4096 -> 2x blocks, atomicAdd into zeroed op
  zero_f32<<<PAIR_CAP * CDIM / 1024, 256, 0, stream>>>((float4*)op);
  gemm128<2, 0, true, 2><<<dim3(CDIM / 128, 16, 18), 256, 0, stream>>>(
      h, ew2T, sw2T, eb2, sb2, op, meta, nullptr, CDIM, IDIM);

  combine_out<<<TOK, 256, 0, stream>>>(op, pair_pos, tok_w, (float*)d_out);
}

// Round 2
// 698.432 us; speedup vs baseline: 1.9444x; 1.0002x over previous
//
#include <hip/hip_runtime.h>
#include <cstdint>
#include <cstddef>
#include <cstdio>

#define DI __device__ __forceinline__

typedef __attribute__((ext_vector_type(4))) float f32x4;
typedef __attribute__((ext_vector_type(8))) short bf16x8;

static constexpr int TOK  = 2048;   // B*T
static constexpr int CDIM = 1024;
static constexpr int IDIM = 4096;
static constexpr int RHID = 256;    // router hidden
static constexpr int RK   = 4096;   // router split-K: [xhi|xhi|xlo|xlo]·[whi|wlo|whi|wlo]
static constexpr int PAIR_CAP = 2048 + 4096 + 8 * 128;  // shared + routed + pad = 7168

DI float bf2f(unsigned short u) {
  unsigned int v = ((unsigned int)u) << 16;
  float f; __builtin_memcpy(&f, &v, sizeof(f));
  return f;
}
DI unsigned short f2bf(float f) {
  unsigned int u; __builtin_memcpy(&u, &f, sizeof(u));
  u += 0x7fffu + ((u >> 16) & 1u);   // RNE
  return (unsigned short)(u >> 16);
}

// async global->LDS DMA, 16B per lane. LDS dest must be wave-uniform base + lane*16.
DI void gload16(const unsigned short* g, unsigned short* l) {
  unsigned short* gm = const_cast<unsigned short*>(g);
  __builtin_amdgcn_global_load_lds(
      (__attribute__((address_space(1))) void*)gm,
      (__attribute__((address_space(3))) void*)l, 16, 0, 0);
}

// ---- x (fp32) -> xb (bf16), xcat (bf16 [2048][4096] = [hi|hi|lo|lo]) ----
__global__ void cvt_x_k(const float* __restrict__ x, unsigned short* __restrict__ xb,
                        unsigned short* __restrict__ xcat) {
  const int i = (blockIdx.x * 256 + threadIdx.x) * 4;   // over 2048*1024 elems
  const float4 v = *(const float4*)(x + i);
  unsigned short hi[4], lo[4];
  const float vf[4] = {v.x, v.y, v.z, v.w};
#pragma unroll
  for (int j = 0; j < 4; ++j) {
    hi[j] = f2bf(vf[j]);
    lo[j] = f2bf(vf[j] - bf2f(hi[j]));
  }
  const int row = i >> 10, col = i & 1023;
  *(uint2*)(xb + (size_t)row * CDIM + col) = *(const uint2*)hi;
  unsigned short* xr = xcat + (size_t)row * RK;
  *(uint2*)(xr + col)        = *(const uint2*)hi;
  *(uint2*)(xr + col + 1024) = *(const uint2*)hi;
  *(uint2*)(xr + col + 2048) = *(const uint2*)lo;
  *(uint2*)(xr + col + 3072) = *(const uint2*)lo;
}

// ---- fp32 src[R][Cc] -> bf16 dst[Cc][R] (transpose + downcast), batched z ----
__global__ void transpose_f2b_k(const float* __restrict__ src, unsigned short* __restrict__ dst,
                                int R, int Cc) {
  __shared__ float tile[64][65];
  src += (size_t)blockIdx.z * R * Cc;
  dst += (size_t)blockIdx.z * R * Cc;
  const int c0 = blockIdx.x * 64, r0 = blockIdx.y * 64;
  const int t = threadIdx.x;
  const int tr = t >> 4, tc = (t & 15) * 4;
#pragma unroll
  for (int it = 0; it < 4; ++it) {
    const int r = tr + it * 16;
    const float4 v = *(const float4*)(src + (size_t)(r0 + r) * Cc + c0 + tc);
    tile[r][tc] = v.x; tile[r][tc + 1] = v.y; tile[r][tc + 2] = v.z; tile[r][tc + 3] = v.w;
  }
  __syncthreads();
  const int j0 = (t & 7) * 8;
#pragma unroll
  for (int it = 0; it < 2; ++it) {
    const int cl = (t >> 3) + it * 32;
    unsigned short tmp[8];
#pragma unroll
    for (int j = 0; j < 8; ++j) tmp[j] = f2bf(tile[j0 + j][cl]);
    *(uint4*)(dst + (size_t)(c0 + cl) * R + r0 + j0) = *(const uint4*)tmp;
  }
}

// ---- rw1 fp32 [1024][256] -> wcat bf16 [256][4096] = [whi|wlo|whi|wlo] ----
__global__ void router_w_prep(const float* __restrict__ src, unsigned short* __restrict__ dst) {
  __shared__ float tile[64][65];
  const int Cc = RHID;
  const int c0 = blockIdx.x * 64, r0 = blockIdx.y * 64;
  const int t = threadIdx.x;
  const int tr = t >> 4, tc = (t & 15) * 4;
#pragma unroll
  for (int it = 0; it < 4; ++it) {
    const int r = tr + it * 16;
    const float4 v = *(const float4*)(src + (size_t)(r0 + r) * Cc + c0 + tc);
    tile[r][tc] = v.x; tile[r][tc + 1] = v.y; tile[r][tc + 2] = v.z; tile[r][tc + 3] = v.w;
  }
  __syncthreads();
  const int j0 = (t & 7) * 8;
#pragma unroll
  for (int it = 0; it < 2; ++it) {
    const int cl = (t >> 3) + it * 32;
    unsigned short hi[8], lo[8];
#pragma unroll
    for (int j = 0; j < 8; ++j) {
      const float v = tile[j0 + j][cl];
      hi[j] = f2bf(v);
      lo[j] = f2bf(v - bf2f(hi[j]));
    }
    unsigned short* dr = dst + (size_t)(c0 + cl) * RK + r0 + j0;
    *(uint4*)(dr)        = *(const uint4*)hi;
    *(uint4*)(dr + 1024) = *(const uint4*)lo;
    *(uint4*)(dr + 2048) = *(const uint4*)hi;
    *(uint4*)(dr + 3072) = *(const uint4*)lo;
  }
}

__global__ void zero_f32(float4* __restrict__ p) {
  p[(size_t)blockIdx.x * 256 + threadIdx.x] = make_float4(0.f, 0.f, 0.f, 0.f);
}

// ---------------- small setup kernels ----------------
// meta: [0..7] counts, [8..15] fill, [16..23] row offsets, [32..39] tiles
__global__ void init_meta(int* __restrict__ meta, int* __restrict__ pair_token) {
  const int i = blockIdx.x * 256 + threadIdx.x;
  if (i < 64) meta[i] = 0;
  if (i < PAIR_CAP) pair_token[i] = (i < TOK) ? i : 0;
}

__global__ void router_finish(const float* __restrict__ rh,
                              const float* __restrict__ rw2,
                              const float* __restrict__ rb2,
                              int* __restrict__ tok_e, float* __restrict__ tok_w,
                              int* __restrict__ meta) {
  const int wave = threadIdx.x >> 6, lane = threadIdx.x & 63;
  const int t = blockIdx.x * 4 + wave;
  float a[8] = {0, 0, 0, 0, 0, 0, 0, 0};
  const float* hp = rh + (size_t)t * RHID;
#pragma unroll
  for (int it = 0; it < 4; ++it) {
    const int j = it * 64 + lane;
    const float hv = fmaxf(hp[j], 0.0f);          // relu moved here (gemm is split-K linear)
    const float4 wa = *(const float4*)(rw2 + (size_t)j * 8);
    const float4 wb = *(const float4*)(rw2 + (size_t)j * 8 + 4);
    a[0] += hv * wa.x; a[1] += hv * wa.y; a[2] += hv * wa.z; a[3] += hv * wa.w;
    a[4] += hv * wb.x; a[5] += hv * wb.y; a[6] += hv * wb.z; a[7] += hv * wb.w;
  }
#pragma unroll
  for (int off = 32; off > 0; off >>= 1)
#pragma unroll
    for (int e = 0; e < 8; ++e) a[e] += __shfl_down(a[e], off);
  if (lane == 0) {
    float lg[8], mx = -1e30f;
#pragma unroll
    for (int e = 0; e < 8; ++e) { lg[e] = a[e] + rb2[e]; mx = fmaxf(mx, lg[e]); }
    float s = 0.f;
#pragma unroll
    for (int e = 0; e < 8; ++e) { lg[e] = __expf(lg[e] - mx); s += lg[e]; }
    const float inv = 1.f / s;
#pragma unroll
    for (int e = 0; e < 8; ++e) lg[e] *= inv;
    int e1 = 0; float g1 = lg[0];
#pragma unroll
    for (int e = 1; e < 8; ++e) if (lg[e] > g1) { g1 = lg[e]; e1 = e; }
    int e2 = -1; float g2 = -1e30f;
#pragma unroll
    for (int e = 0; e < 8; ++e) if (e != e1 && lg[e] > g2) { g2 = lg[e]; e2 = e; }
    const float eb = __expf((g2 - g1) * 0.5f);
    const float w1 = 1.f / (1.f + eb), w2 = eb / (1.f + eb);
    tok_e[2 * t] = e1; tok_e[2 * t + 1] = e2;
    tok_w[2 * t] = w1; tok_w[2 * t + 1] = w2;
    atomicAdd(&meta[e1], 1); atomicAdd(&meta[e2], 1);
  }
}

__global__ void compute_offsets(int* __restrict__ meta) {
  if (threadIdx.x == 0) {
    int o = TOK;
    for (int e = 0; e < 8; ++e) {
      meta[16 + e] = o;
      const int tl = (meta[e] + 127) >> 7;
      meta[32 + e] = tl;
      o += tl << 7;
    }
  }
}

__global__ void scatter_pairs(const int* __restrict__ tok_e, int* __restrict__ meta,
                              int* __restrict__ pair_token, int* __restrict__ pair_pos) {
  const int t = blockIdx.x * 256 + threadIdx.x;
#pragma unroll
  for (int k = 0; k < 2; ++k) {
    const int e = tok_e[2 * t + k];
    const int pos = meta[16 + e] + atomicAdd(&meta[8 + e], 1);
    pair_token[pos] = t;
    pair_pos[2 * t + k] = pos;
  }
}

// ---------------- 128x128 MFMA GEMM, C = act(A @ Bt^T + bias) ----------------
// MODE 0: plain (router). MODE 1: MoE gather x->h. MODE 2: MoE h->op.
// Bt is [N][K] row-major bf16. zz==8 selects the shared expert. Biases fp32.
// SPLIT>1: split-K with fp32 atomicAdd into pre-zeroed Cout (ACT must be 0);
//   MODE 0: blockIdx.z = split index; MODE 2: blockIdx.z = expert + 9*split.
// K-loop: 3-buffer LDS, depth-2 global_load_lds pipeline, counted vmcnt(4)
// (T3/T4: loads stay in flight across the raw s_barrier; never drain to 0).
template <int MODE, int ACT, bool OUTF32, int SPLIT>
__global__ __launch_bounds__(256) void gemm128(
    const unsigned short* __restrict__ A,
    const unsigned short* __restrict__ BtE, const unsigned short* __restrict__ BtS,
    const float* __restrict__ biasE, const float* __restrict__ biasS,
    void* __restrict__ Cout,
    const int* __restrict__ meta, const int* __restrict__ pair_token,
    int N, int K) {
  __shared__ unsigned short Alds[3][128 * 32];
  __shared__ unsigned short Blds[3][128 * 32];

  const int tid = threadIdx.x, wave = tid >> 6, lane = tid & 63;

  int ks = 0, zz = blockIdx.z;
  if (MODE == 0) {
    ks = zz;
  } else if (SPLIT > 1) {
    ks = zz / 9; zz -= ks * 9;
  }

  const unsigned short* Bt;
  const float* bias;
  int row0;
  if (MODE == 0) {
    row0 = blockIdx.y * 128; Bt = BtE; bias = biasE;
  } else {
    if (zz < 8) {
      if ((int)blockIdx.y >= meta[32 + zz]) return;
      row0 = meta[16 + zz] + blockIdx.y * 128;
      Bt = BtE + (size_t)zz * N * K;
      bias = biasE + zz * N;
    } else {
      row0 = blockIdx.y * 128;
      Bt = BtS; bias = biasS;
    }
  }
  const int n0 = blockIdx.x * 128;
  const int Kc = K / SPLIT;
  const size_t kbase = (size_t)ks * Kc;

  // chunk q (0..511): row m=q>>2; LDS slot q&3 (linear in lane order -> DMA-compatible)
  // holds global data chunk c = (q&3) ^ ((m>>1)&3)  [XOR-swizzled SOURCE, rule #21]
  const unsigned short* aSrc[2];
  const unsigned short* bSrc[2];
  int ldsOff[2];
#pragma unroll
  for (int i = 0; i < 2; ++i) {
    const int q = i * 256 + tid;
    const int m = q >> 2;
    const int c = (q & 3) ^ ((m >> 1) & 3);
    const size_t arow = (MODE == 1) ? (size_t)pair_token[row0 + m] : (size_t)(row0 + m);
    aSrc[i] = A + arow * K + kbase + c * 8;
    bSrc[i] = Bt + (size_t)(n0 + m) * K + kbase + c * 8;
    ldsOff[i] = q * 8;
  }

  const int wr = wave >> 1, wc = wave & 1;
  int aOff[4], bOff[4];
#pragma unroll
  for (int t = 0; t < 4; ++t) {
    const int ar = wr * 64 + t * 16 + (lane & 15);
    aOff[t] = (ar * 4 + ((lane >> 4) ^ ((ar >> 1) & 3))) * 8;
    const int br = wc * 64 + t * 16 + (lane & 15);
    bOff[t] = (br * 4 + ((lane >> 4) ^ ((br >> 1) & 3))) * 8;
  }

  f32x4 acc[4][4] = {};
  const int kIters = Kc >> 5;

  // prologue: stage tiles 0,1 into buffers 0,1 (8 DMAs in flight)
#pragma unroll
  for (int i = 0; i < 2; ++i) {
    gload16(aSrc[i], &Alds[0][ldsOff[i]]);
    gload16(bSrc[i], &Blds[0][ldsOff[i]]);
  }
  if (kIters > 1) {
#pragma unroll
    for (int i = 0; i < 2; ++i) {
      gload16(aSrc[i] + 32, &Alds[1][ldsOff[i]]);
      gload16(bSrc[i] + 32, &Blds[1][ldsOff[i]]);
    }
  }

  int cur = 0;
  for (int kk = 0; kk < kIters; ++kk) {
    // tile kk landed (its 4 DMAs are the oldest); tile kk+1's 4 stay in flight
    if (kk + 1 < kIters) asm volatile("s_waitcnt vmcnt(4)" ::: "memory");
    else                 asm volatile("s_waitcnt vmcnt(0)" ::: "memory");
    __builtin_amdgcn_s_barrier();
    asm volatile("" ::: "memory");
    if (kk + 2 < kIters) {
      // buffer (cur+2)%3 was last read in iteration kk-1; all reads done at the
      // barrier above -> safe to overwrite now, lands under 2 compute phases
      int ib = cur + 2; if (ib >= 3) ib -= 3;
      const int ko = (kk + 2) * 32;
#pragma unroll
      for (int i = 0; i < 2; ++i) {
        gload16(aSrc[i] + ko, &Alds[ib][ldsOff[i]]);
        gload16(bSrc[i] + ko, &Blds[ib][ldsOff[i]]);
      }
    }
    bf16x8 af[4], bfr[4];
#pragma unroll
    for (int t = 0; t < 4; ++t) {
      af[t]  = *(const bf16x8*)(&Alds[cur][aOff[t]]);
      bfr[t] = *(const bf16x8*)(&Blds[cur][bOff[t]]);
    }
    __builtin_amdgcn_s_setprio(1);
#pragma unroll
    for (int mt = 0; mt < 4; ++mt)
#pragma unroll
      for (int nt = 0; nt < 4; ++nt)
        acc[mt][nt] = __builtin_amdgcn_mfma_f32_16x16x32_bf16(af[mt], bfr[nt], acc[mt][nt], 0, 0, 0);
    __builtin_amdgcn_s_setprio(0);
    ++cur; if (cur >= 3) cur = 0;
  }

  float bv[4];
  const bool addb = (SPLIT == 1) || (ks == 0);
#pragma unroll
  for (int nt = 0; nt < 4; ++nt)
    bv[nt] = addb ? bias[n0 + wc * 64 + nt * 16 + (lane & 15)] : 0.0f;

  // C/D layout: col = lane&15, row = (lane>>4)*4 + reg  [m89-verified]
  const int rb = row0 + wr * 64 + ((lane >> 4) * 4);
  const int cb = n0 + wc * 64 + (lane & 15);
#pragma unroll
  for (int mt = 0; mt < 4; ++mt)
#pragma unroll
    for (int nt = 0; nt < 4; ++nt)
#pragma unroll
      for (int r = 0; r < 4; ++r) {
        float v = acc[mt][nt][r] + bv[nt];
        if (ACT == 1) v = fmaxf(v, 0.0f);
        if (ACT == 2) v = v / (1.0f + __expf(-v));   // silu
        const size_t idx = (size_t)(rb + mt * 16 + r) * (size_t)N + (size_t)(cb + nt * 16);
        if (SPLIT > 1)   atomicAdd((float*)Cout + idx, v);
        else if (OUTF32) ((float*)Cout)[idx] = v;
        else             ((unsigned short*)Cout)[idx] = f2bf(v);
      }
}

// ---------------- final combine: y = shared + w0*pair0 + w1*pair1 (fp32 out) ----------------
__global__ void combine_out(const float* __restrict__ op, const int* __restrict__ pair_pos,
                            const float* __restrict__ tok_w, float* __restrict__ y) {
  const int t = blockIdx.x;
  const int c = threadIdx.x * 4;
  const int p0 = pair_pos[2 * t], p1 = pair_pos[2 * t + 1];
  const float w0 = tok_w[2 * t], w1 = tok_w[2 * t + 1];
  const float4 vs = *(const float4*)(op + (size_t)t  * CDIM + c);
  const float4 va = *(const float4*)(op + (size_t)p0 * CDIM + c);
  const float4 vb = *(const float4*)(op + (size_t)p1 * CDIM + c);
  float4 o;
  o.x = vs.x + w0 * va.x + w1 * vb.x;
  o.y = vs.y + w0 * va.y + w1 * vb.y;
  o.z = vs.z + w0 * va.z + w1 * vb.z;
  o.w = vs.w + w0 * va.w + w1 * vb.w;
  *(float4*)(y + (size_t)t * CDIM + c) = o;
}

extern "C" void kernel_launch(void* const* d_in, const int* in_sizes, int n_in,
                              void* d_out, int out_size, void* d_ws, size_t ws_size,
                              hipStream_t stream) {
  const float* x   = (const float*)d_in[0];
  const float* rw1 = (const float*)d_in[1];
  const float* rb1 = (const float*)d_in[2];
  const float* rw2 = (const float*)d_in[3];
  const float* rb2 = (const float*)d_in[4];
  const float* ew1 = (const float*)d_in[5];
  const float* eb1 = (const float*)d_in[6];
  const float* ew2 = (const float*)d_in[7];
  const float* eb2 = (const float*)d_in[8];
  const float* sw1 = (const float*)d_in[9];
  const float* sb1 = (const float*)d_in[10];
  const float* sw2 = (const float*)d_in[11];
  const float* sb2 = (const float*)d_in[12];

  char* w = (char*)d_ws;
  auto alloc = [&](size_t bytes) {
    char* p = w; w += (bytes + 255) & ~(size_t)255; return p;
  };
  unsigned short* ew1T = (unsigned short*)alloc(8ull * IDIM * CDIM * 2);   // [e][I][C] bf16
  unsigned short* ew2T = (unsigned short*)alloc(8ull * CDIM * IDIM * 2);   // [e][C][I] bf16
  unsigned short* sw1T = (unsigned short*)alloc((size_t)IDIM * CDIM * 2);
  unsigned short* sw2T = (unsigned short*)alloc((size_t)CDIM * IDIM * 2);
  unsigned short* h    = (unsigned short*)alloc((size_t)PAIR_CAP * IDIM * 2);
  float* op            = (float*)alloc((size_t)PAIR_CAP * CDIM * 4);
  float* tok_w         = (float*)alloc(2 * TOK * 4);
  int*   tok_e         = (int*)alloc(2 * TOK * 4);
  int*   meta          = (int*)alloc(64 * 4);
  int*   pair_token    = (int*)alloc(PAIR_CAP * 4);
  int*   pair_pos      = (int*)alloc(2 * TOK * 4);
  const size_t need = (size_t)(w - (char*)d_ws);
  if (need > ws_size) {
    fprintf(stderr, "kernel_launch: ws too small: need %zu have %zu\n", need, ws_size);
    return;
  }
  // Aliased scratch (dead before their hosts are written, stream-ordered):
  //   xcat (16.8 MB) lives in h (58.7 MB) — h written by GEMM1, after router consumes xcat
  //   wcat @ op+0 (2.1 MB), rh @ op+4MB (2.1 MB), xb @ op+8MB (4.2 MB) — op zeroed+written
  //   only after GEMM1 (which is the last consumer of xb)
  unsigned short* xcat = (unsigned short*)h;
  unsigned short* wcat = (unsigned short*)((char*)op);
  float*          rh   = (float*)((char*)op + (4ull << 20));
  unsigned short* xb   = (unsigned short*)((char*)op + (8ull << 20));

  // fp32 -> bf16 conversions (+ transposes): weights and activations
  cvt_x_k<<<TOK * CDIM / 1024, 256, 0, stream>>>(x, xb, xcat);
  router_w_prep<<<dim3(RHID / 64, CDIM / 64, 1), 256, 0, stream>>>(rw1, wcat);
  transpose_f2b_k<<<dim3(IDIM / 64, CDIM / 64, 8), 256, 0, stream>>>(ew1, ew1T, CDIM, IDIM);
  transpose_f2b_k<<<dim3(CDIM / 64, IDIM / 64, 8), 256, 0, stream>>>(ew2, ew2T, IDIM, CDIM);
  transpose_f2b_k<<<dim3(IDIM / 64, CDIM / 64, 1), 256, 0, stream>>>(sw1, sw1T, CDIM, IDIM);
  transpose_f2b_k<<<dim3(CDIM / 64, IDIM / 64, 1), 256, 0, stream>>>(sw2, sw2T, IDIM, CDIM);

  init_meta<<<PAIR_CAP / 256, 256, 0, stream>>>(meta, pair_token);

  // router hidden: rh = x @ rw1 + rb1 (linear; relu applied in router_finish)
  // split-K=8 over RK=4096 -> 256 blocks, atomicAdd into zeroed rh
  zero_f32<<<TOK * RHID / 1024, 256, 0, stream>>>((float4*)rh);
  gemm128<0, 0, true, 8><<<dim3(RHID / 128, TOK / 128, 8), 256, 0, stream>>>(
      xcat, wcat, nullptr, rb1, nullptr, rh, nullptr, nullptr, RHID, RK);
  router_finish<<<TOK / 4, 256, 0, stream>>>(rh, rw2, rb2, tok_e, tok_w, meta);
  compute_offsets<<<1, 64, 0, stream>>>(meta);
  scatter_pairs<<<TOK / 256, 256, 0, stream>>>(tok_e, meta, pair_token, pair_pos);

  // expert FFN (zz = 0..7 routed experts, zz = 8 shared expert over all tokens)
  gemm128<1, 2, false, 1><<<dim3(IDIM / 128, 16, 9), 256, 0, stream>>>(
      xb, ew1T, sw1T, eb1, sb1, h, meta, pair_token, IDIM, CDIM);
  // GEMM2: split-K=2 over IDIM=4096 -> 2x blocks, atomicAdd into zeroed op
  zero_f32<<<PAIR_CAP * CDIM / 1024, 256, 0, stream>>>((float4*)op);
  gemm128<2, 0, true, 2><<<dim3(CDIM / 128, 16, 18), 256, 0, stream>>>(
      h, ew2T, sw2T, eb2, sb2, op, meta, nullptr, CDIM, IDIM);

  combine_out<<<TOK, 256, 0, stream>>>(op, pair_pos, tok_w, (float*)d_out);
}

// Round 3
// 646.233 us; speedup vs baseline: 2.1015x; 1.0808x over previous
//
#include <hip/hip_runtime.h>
#include <cstdint>
#include <cstddef>
#include <cstdio>

#define DI __device__ __forceinline__

typedef __attribute__((ext_vector_type(4))) float f32x4;
typedef __attribute__((ext_vector_type(8))) short bf16x8;
typedef __attribute__((address_space(3))) const unsigned short* lds_cp;

static constexpr int TOK  = 2048;   // B*T
static constexpr int CDIM = 1024;
static constexpr int IDIM = 4096;
static constexpr int RHID = 256;    // router hidden
static constexpr int RK   = 4096;   // router split-K: [xhi|xhi|xlo|xlo]·[whi|wlo|whi|wlo]
static constexpr int PAIR_CAP = 2048 + 4096 + 8 * 128;  // shared + routed + pad = 7168

DI float bf2f(unsigned short u) {
  unsigned int v = ((unsigned int)u) << 16;
  float f; __builtin_memcpy(&f, &v, sizeof(f));
  return f;
}
DI unsigned short f2bf(float f) {
  unsigned int u; __builtin_memcpy(&u, &f, sizeof(u));
  u += 0x7fffu + ((u >> 16) & 1u);   // RNE
  return (unsigned short)(u >> 16);
}

// async global->LDS DMA, 16B per lane. LDS dest must be wave-uniform base + lane*16.
DI void gload16(const unsigned short* g, unsigned short* l) {
  unsigned short* gm = const_cast<unsigned short*>(g);
  __builtin_amdgcn_global_load_lds(
      (__attribute__((address_space(1))) void*)gm,
      (__attribute__((address_space(3))) void*)l, 16, 0, 0);
}

// ---- x (fp32) -> xb (bf16), xcat (bf16 [2048][4096] = [hi|hi|lo|lo]) ----
__global__ void cvt_x_k(const float* __restrict__ x, unsigned short* __restrict__ xb,
                        unsigned short* __restrict__ xcat) {
  const int i = (blockIdx.x * 256 + threadIdx.x) * 4;   // over 2048*1024 elems
  const float4 v = *(const float4*)(x + i);
  unsigned short hi[4], lo[4];
  const float vf[4] = {v.x, v.y, v.z, v.w};
#pragma unroll
  for (int j = 0; j < 4; ++j) {
    hi[j] = f2bf(vf[j]);
    lo[j] = f2bf(vf[j] - bf2f(hi[j]));
  }
  const int row = i >> 10, col = i & 1023;
  *(uint2*)(xb + (size_t)row * CDIM + col) = *(const uint2*)hi;
  unsigned short* xr = xcat + (size_t)row * RK;
  *(uint2*)(xr + col)        = *(const uint2*)hi;
  *(uint2*)(xr + col + 1024) = *(const uint2*)hi;
  *(uint2*)(xr + col + 2048) = *(const uint2*)lo;
  *(uint2*)(xr + col + 3072) = *(const uint2*)lo;
}

// ---- fp32 src[R][Cc] -> bf16 dst[Cc][R] (transpose + downcast), batched z ----
__global__ void transpose_f2b_k(const float* __restrict__ src, unsigned short* __restrict__ dst,
                                int R, int Cc) {
  __shared__ float tile[64][65];
  src += (size_t)blockIdx.z * R * Cc;
  dst += (size_t)blockIdx.z * R * Cc;
  const int c0 = blockIdx.x * 64, r0 = blockIdx.y * 64;
  const int t = threadIdx.x;
  const int tr = t >> 4, tc = (t & 15) * 4;
#pragma unroll
  for (int it = 0; it < 4; ++it) {
    const int r = tr + it * 16;
    const float4 v = *(const float4*)(src + (size_t)(r0 + r) * Cc + c0 + tc);
    tile[r][tc] = v.x; tile[r][tc + 1] = v.y; tile[r][tc + 2] = v.z; tile[r][tc + 3] = v.w;
  }
  __syncthreads();
  const int j0 = (t & 7) * 8;
#pragma unroll
  for (int it = 0; it < 2; ++it) {
    const int cl = (t >> 3) + it * 32;
    unsigned short tmp[8];
#pragma unroll
    for (int j = 0; j < 8; ++j) tmp[j] = f2bf(tile[j0 + j][cl]);
    *(uint4*)(dst + (size_t)(c0 + cl) * R + r0 + j0) = *(const uint4*)tmp;
  }
}

// ---- rw1 fp32 [1024][256] -> wcat bf16 [256][4096] = [whi|wlo|whi|wlo] ----
__global__ void router_w_prep(const float* __restrict__ src, unsigned short* __restrict__ dst) {
  __shared__ float tile[64][65];
  const int Cc = RHID;
  const int c0 = blockIdx.x * 64, r0 = blockIdx.y * 64;
  const int t = threadIdx.x;
  const int tr = t >> 4, tc = (t & 15) * 4;
#pragma unroll
  for (int it = 0; it < 4; ++it) {
    const int r = tr + it * 16;
    const float4 v = *(const float4*)(src + (size_t)(r0 + r) * Cc + c0 + tc);
    tile[r][tc] = v.x; tile[r][tc + 1] = v.y; tile[r][tc + 2] = v.z; tile[r][tc + 3] = v.w;
  }
  __syncthreads();
  const int j0 = (t & 7) * 8;
#pragma unroll
  for (int it = 0; it < 2; ++it) {
    const int cl = (t >> 3) + it * 32;
    unsigned short hi[8], lo[8];
#pragma unroll
    for (int j = 0; j < 8; ++j) {
      const float v = tile[j0 + j][cl];
      hi[j] = f2bf(v);
      lo[j] = f2bf(v - bf2f(hi[j]));
    }
    unsigned short* dr = dst + (size_t)(c0 + cl) * RK + r0 + j0;
    *(uint4*)(dr)        = *(const uint4*)hi;
    *(uint4*)(dr + 1024) = *(const uint4*)lo;
    *(uint4*)(dr + 2048) = *(const uint4*)hi;
    *(uint4*)(dr + 3072) = *(const uint4*)lo;
  }
}

// ---------------- small setup kernels ----------------
// meta: [0..7] counts, [8..15] fill, [16..23] row offsets, [32..39] tiles
__global__ void init_meta(int* __restrict__ meta, int* __restrict__ pair_token) {
  const int i = blockIdx.x * 256 + threadIdx.x;
  if (i < 64) meta[i] = 0;
  if (i < PAIR_CAP) pair_token[i] = (i < TOK) ? i : 0;
}

// rh has 8 split-K slabs [s][TOK][RHID]; sum + relu here.
__global__ void router_finish(const float* __restrict__ rh,
                              const float* __restrict__ rw2,
                              const float* __restrict__ rb2,
                              int* __restrict__ tok_e, float* __restrict__ tok_w,
                              int* __restrict__ meta) {
  const int wave = threadIdx.x >> 6, lane = threadIdx.x & 63;
  const int t = blockIdx.x * 4 + wave;
  float a[8] = {0, 0, 0, 0, 0, 0, 0, 0};
  const float* hp = rh + (size_t)t * RHID;
#pragma unroll
  for (int it = 0; it < 4; ++it) {
    const int j = it * 64 + lane;
    float hv = hp[j];
#pragma unroll
    for (int s = 1; s < 8; ++s) hv += hp[j + (size_t)s * TOK * RHID];
    hv = fmaxf(hv, 0.0f);          // relu (bias is in slab 0)
    const float4 wa = *(const float4*)(rw2 + (size_t)j * 8);
    const float4 wb = *(const float4*)(rw2 + (size_t)j * 8 + 4);
    a[0] += hv * wa.x; a[1] += hv * wa.y; a[2] += hv * wa.z; a[3] += hv * wa.w;
    a[4] += hv * wb.x; a[5] += hv * wb.y; a[6] += hv * wb.z; a[7] += hv * wb.w;
  }
#pragma unroll
  for (int off = 32; off > 0; off >>= 1)
#pragma unroll
    for (int e = 0; e < 8; ++e) a[e] += __shfl_down(a[e], off);
  if (lane == 0) {
    float lg[8], mx = -1e30f;
#pragma unroll
    for (int e = 0; e < 8; ++e) { lg[e] = a[e] + rb2[e]; mx = fmaxf(mx, lg[e]); }
    float s = 0.f;
#pragma unroll
    for (int e = 0; e < 8; ++e) { lg[e] = __expf(lg[e] - mx); s += lg[e]; }
    const float inv = 1.f / s;
#pragma unroll
    for (int e = 0; e < 8; ++e) lg[e] *= inv;
    int e1 = 0; float g1 = lg[0];
#pragma unroll
    for (int e = 1; e < 8; ++e) if (lg[e] > g1) { g1 = lg[e]; e1 = e; }
    int e2 = -1; float g2 = -1e30f;
#pragma unroll
    for (int e = 0; e < 8; ++e) if (e != e1 && lg[e] > g2) { g2 = lg[e]; e2 = e; }
    const float eb = __expf((g2 - g1) * 0.5f);
    const float w1 = 1.f / (1.f + eb), w2 = eb / (1.f + eb);
    tok_e[2 * t] = e1; tok_e[2 * t + 1] = e2;
    tok_w[2 * t] = w1; tok_w[2 * t + 1] = w2;
    atomicAdd(&meta[e1], 1); atomicAdd(&meta[e2], 1);
  }
}

__global__ void compute_offsets(int* __restrict__ meta) {
  if (threadIdx.x == 0) {
    int o = TOK;
    for (int e = 0; e < 8; ++e) {
      meta[16 + e] = o;
      const int tl = (meta[e] + 127) >> 7;
      meta[32 + e] = tl;
      o += tl << 7;
    }
  }
}

__global__ void scatter_pairs(const int* __restrict__ tok_e, int* __restrict__ meta,
                              int* __restrict__ pair_token, int* __restrict__ pair_pos) {
  const int t = blockIdx.x * 256 + threadIdx.x;
#pragma unroll
  for (int k = 0; k < 2; ++k) {
    const int e = tok_e[2 * t + k];
    const int pos = meta[16 + e] + atomicAdd(&meta[8 + e], 1);
    pair_token[pos] = t;
    pair_pos[2 * t + k] = pos;
  }
}

// ---------------- 128x128 MFMA GEMM, C = act(A @ Bt^T + bias) ----------------
// MODE 0: plain (router). MODE 1: MoE gather x->h. MODE 2: MoE h->op.
// Bt is [N][K] row-major bf16. zz==8 selects the shared expert. Biases fp32.
// SPLIT>1: split-K writing to DISJOINT fp32 slabs Cout + ks*slabStride (no atomics;
//   consumer sums). Bias added only in slab 0. MODE 0: z = split; MODE 2: z = e + 9*split.
// K-loop: 3-buffer LDS, depth-2 global_load_lds pipeline; ALL waits via inline asm
// (counted vmcnt(4) + raw s_barrier) and LDS reads via asm ds_read_b128 so the
// compiler cannot re-insert vmcnt(0) drains (rule #18: lgkmcnt + sched_barrier).
template <int MODE, int ACT, bool OUTF32, int SPLIT>
__global__ __launch_bounds__(256) void gemm128(
    const unsigned short* __restrict__ A,
    const unsigned short* __restrict__ BtE, const unsigned short* __restrict__ BtS,
    const float* __restrict__ biasE, const float* __restrict__ biasS,
    void* __restrict__ Cout,
    const int* __restrict__ meta, const int* __restrict__ pair_token,
    int N, int K, int slabStride) {
  __shared__ unsigned short Alds[3][128 * 32];
  __shared__ unsigned short Blds[3][128 * 32];

  const int tid = threadIdx.x, wave = tid >> 6, lane = tid & 63;

  int ks = 0, zz = blockIdx.z;
  if (MODE == 0) {
    ks = zz;
  } else if (SPLIT > 1) {
    ks = zz / 9; zz -= ks * 9;
  }

  const unsigned short* Bt;
  const float* bias;
  int row0;
  if (MODE == 0) {
    row0 = blockIdx.y * 128; Bt = BtE; bias = biasE;
  } else {
    if (zz < 8) {
      if ((int)blockIdx.y >= meta[32 + zz]) return;
      row0 = meta[16 + zz] + blockIdx.y * 128;
      Bt = BtE + (size_t)zz * N * K;
      bias = biasE + zz * N;
    } else {
      row0 = blockIdx.y * 128;
      Bt = BtS; bias = biasS;
    }
  }
  const int n0 = blockIdx.x * 128;
  const int Kc = K / SPLIT;
  const size_t kbase = (size_t)ks * Kc;

  // chunk q (0..511): row m=q>>2; LDS slot q&3 (linear in lane order -> DMA-compatible)
  // holds global data chunk c = (q&3) ^ ((m>>1)&3)  [XOR-swizzled SOURCE, rule #21]
  const unsigned short* aSrc[2];
  const unsigned short* bSrc[2];
  int ldsOff[2];
#pragma unroll
  for (int i = 0; i < 2; ++i) {
    const int q = i * 256 + tid;
    const int m = q >> 2;
    const int c = (q & 3) ^ ((m >> 1) & 3);
    const size_t arow = (MODE == 1) ? (size_t)pair_token[row0 + m] : (size_t)(row0 + m);
    aSrc[i] = A + arow * K + kbase + c * 8;
    bSrc[i] = Bt + (size_t)(n0 + m) * K + kbase + c * 8;
    ldsOff[i] = q * 8;
  }

  const int wr = wave >> 1, wc = wave & 1;
  int aOff[4], bOff[4];
#pragma unroll
  for (int t = 0; t < 4; ++t) {
    const int ar = wr * 64 + t * 16 + (lane & 15);
    aOff[t] = (ar * 4 + ((lane >> 4) ^ ((ar >> 1) & 3))) * 8;
    const int br = wc * 64 + t * 16 + (lane & 15);
    bOff[t] = (br * 4 + ((lane >> 4) ^ ((br >> 1) & 3))) * 8;
  }

  f32x4 acc[4][4] = {};
  const int kIters = Kc >> 5;

  // prologue: stage tiles 0,1 into buffers 0,1 (8 DMAs in flight)
#pragma unroll
  for (int i = 0; i < 2; ++i) {
    gload16(aSrc[i], &Alds[0][ldsOff[i]]);
    gload16(bSrc[i], &Blds[0][ldsOff[i]]);
  }
  if (kIters > 1) {
#pragma unroll
    for (int i = 0; i < 2; ++i) {
      gload16(aSrc[i] + 32, &Alds[1][ldsOff[i]]);
      gload16(bSrc[i] + 32, &Blds[1][ldsOff[i]]);
    }
  }

  int cur = 0;
  for (int kk = 0; kk < kIters; ++kk) {
    // tile kk's 4 DMAs are the oldest of 8: counted wait keeps kk+1's in flight
    if (kk + 1 < kIters) asm volatile("s_waitcnt vmcnt(4)" ::: "memory");
    else                 asm volatile("s_waitcnt vmcnt(0)" ::: "memory");
    __builtin_amdgcn_s_barrier();
    if (kk + 2 < kIters) {
      // buffer (cur+2)%3 was last read in iter kk-1; those reads completed (each
      // wave's lgkmcnt(0) precedes its barrier arrival) -> safe to overwrite
      int ib = cur + 2; if (ib >= 3) ib -= 3;
      const int ko = (kk + 2) * 32;
#pragma unroll
      for (int i = 0; i < 2; ++i) {
        gload16(aSrc[i] + ko, &Alds[ib][ldsOff[i]]);
        gload16(bSrc[i] + ko, &Blds[ib][ldsOff[i]]);
      }
    }
    bf16x8 af[4], bfr[4];
#pragma unroll
    for (int t = 0; t < 4; ++t) {
      asm volatile("ds_read_b128 %0, %1" : "=v"(af[t])  : "v"((lds_cp)&Alds[cur][aOff[t]]));
      asm volatile("ds_read_b128 %0, %1" : "=v"(bfr[t]) : "v"((lds_cp)&Blds[cur][bOff[t]]));
    }
    asm volatile("s_waitcnt lgkmcnt(0)" ::: "memory");
    __builtin_amdgcn_sched_barrier(0);   // rule #18: MFMA must not hoist above the wait
    __builtin_amdgcn_s_setprio(1);
#pragma unroll
    for (int mt = 0; mt < 4; ++mt)
#pragma unroll
      for (int nt = 0; nt < 4; ++nt)
        acc[mt][nt] = __builtin_amdgcn_mfma_f32_16x16x32_bf16(af[mt], bfr[nt], acc[mt][nt], 0, 0, 0);
    __builtin_amdgcn_s_setprio(0);
    __builtin_amdgcn_sched_barrier(0);   // keep the MFMA cluster inside the phase
    ++cur; if (cur >= 3) cur = 0;
  }

  float bv[4];
  const bool addb = (SPLIT == 1) || (ks == 0);
#pragma unroll
  for (int nt = 0; nt < 4; ++nt)
    bv[nt] = addb ? bias[n0 + wc * 64 + nt * 16 + (lane & 15)] : 0.0f;

  // C/D layout: col = lane&15, row = (lane>>4)*4 + reg  [m89-verified]
  const int rb = row0 + wr * 64 + ((lane >> 4) * 4);
  const int cb = n0 + wc * 64 + (lane & 15);
  float* outp = (float*)Cout + (size_t)ks * (size_t)slabStride;
#pragma unroll
  for (int mt = 0; mt < 4; ++mt)
#pragma unroll
    for (int nt = 0; nt < 4; ++nt)
#pragma unroll
      for (int r = 0; r < 4; ++r) {
        float v = acc[mt][nt][r] + bv[nt];
        if (ACT == 1) v = fmaxf(v, 0.0f);
        if (ACT == 2) v = v / (1.0f + __expf(-v));   // silu
        const size_t idx = (size_t)(rb + mt * 16 + r) * (size_t)N + (size_t)(cb + nt * 16);
        if (OUTF32) outp[idx] = v;
        else        ((unsigned short*)Cout)[idx] = f2bf(v);
      }
}

// ------ final combine: y = Σs shared + w0*Σs pair0 + w1*Σs pair1 (2 op slabs) ------
__global__ void combine_out(const float* __restrict__ op, const int* __restrict__ pair_pos,
                            const float* __restrict__ tok_w, float* __restrict__ y) {
  const int t = blockIdx.x;
  const int c = threadIdx.x * 4;
  const int p0 = pair_pos[2 * t], p1 = pair_pos[2 * t + 1];
  const float w0 = tok_w[2 * t], w1 = tok_w[2 * t + 1];
  const float* op1 = op + (size_t)PAIR_CAP * CDIM;
  const float4 vs0 = *(const float4*)(op  + (size_t)t  * CDIM + c);
  const float4 vs1 = *(const float4*)(op1 + (size_t)t  * CDIM + c);
  const float4 va0 = *(const float4*)(op  + (size_t)p0 * CDIM + c);
  const float4 va1 = *(const float4*)(op1 + (size_t)p0 * CDIM + c);
  const float4 vb0 = *(const float4*)(op  + (size_t)p1 * CDIM + c);
  const float4 vb1 = *(const float4*)(op1 + (size_t)p1 * CDIM + c);
  float4 o;
  o.x = (vs0.x + vs1.x) + w0 * (va0.x + va1.x) + w1 * (vb0.x + vb1.x);
  o.y = (vs0.y + vs1.y) + w0 * (va0.y + va1.y) + w1 * (vb0.y + vb1.y);
  o.z = (vs0.z + vs1.z) + w0 * (va0.z + va1.z) + w1 * (vb0.z + vb1.z);
  o.w = (vs0.w + vs1.w) + w0 * (va0.w + va1.w) + w1 * (vb0.w + vb1.w);
  *(float4*)(y + (size_t)t * CDIM + c) = o;
}

extern "C" void kernel_launch(void* const* d_in, const int* in_sizes, int n_in,
                              void* d_out, int out_size, void* d_ws, size_t ws_size,
                              hipStream_t stream) {
  const float* x   = (const float*)d_in[0];
  const float* rw1 = (const float*)d_in[1];
  const float* rb1 = (const float*)d_in[2];
  const float* rw2 = (const float*)d_in[3];
  const float* rb2 = (const float*)d_in[4];
  const float* ew1 = (const float*)d_in[5];
  const float* eb1 = (const float*)d_in[6];
  const float* ew2 = (const float*)d_in[7];
  const float* eb2 = (const float*)d_in[8];
  const float* sw1 = (const float*)d_in[9];
  const float* sb1 = (const float*)d_in[10];
  const float* sw2 = (const float*)d_in[11];
  const float* sb2 = (const float*)d_in[12];

  char* w = (char*)d_ws;
  auto alloc = [&](size_t bytes) {
    char* p = w; w += (bytes + 255) & ~(size_t)255; return p;
  };
  unsigned short* ew1T = (unsigned short*)alloc(8ull * IDIM * CDIM * 2);   // [e][I][C] bf16
  unsigned short* ew2T = (unsigned short*)alloc(8ull * CDIM * IDIM * 2);   // [e][C][I] bf16
  unsigned short* sw1T = (unsigned short*)alloc((size_t)IDIM * CDIM * 2);
  unsigned short* sw2T = (unsigned short*)alloc((size_t)CDIM * IDIM * 2);
  unsigned short* h    = (unsigned short*)alloc((size_t)PAIR_CAP * IDIM * 2);
  float* op            = (float*)alloc(2ull * PAIR_CAP * CDIM * 4);        // 2 split-K slabs
  float* tok_w         = (float*)alloc(2 * TOK * 4);
  int*   tok_e         = (int*)alloc(2 * TOK * 4);
  int*   meta          = (int*)alloc(64 * 4);
  int*   pair_token    = (int*)alloc(PAIR_CAP * 4);
  int*   pair_pos      = (int*)alloc(2 * TOK * 4);
  const size_t need = (size_t)(w - (char*)d_ws);
  if (need > ws_size) {
    fprintf(stderr, "kernel_launch: ws too small: need %zu have %zu\n", need, ws_size);
    return;
  }
  // Aliased scratch (dead before their hosts are written, stream-ordered):
  //   xcat (16.8 MB) lives in h (58.7 MB) — h written by GEMM1, after router consumes xcat
  //   within op (58.7 MB, written only by GEMM2):
  //     wcat @ +0 (2.1 MB), xb @ +8MB (4.2 MB), rh slabs @ +24MB (8*2.1=16.8 MB)
  unsigned short* xcat = (unsigned short*)h;
  unsigned short* wcat = (unsigned short*)((char*)op);
  unsigned short* xb   = (unsigned short*)((char*)op + (8ull << 20));
  float*          rh   = (float*)((char*)op + (24ull << 20));

  // fp32 -> bf16 conversions (+ transposes): weights and activations
  cvt_x_k<<<TOK * CDIM / 1024, 256, 0, stream>>>(x, xb, xcat);
  router_w_prep<<<dim3(RHID / 64, CDIM / 64, 1), 256, 0, stream>>>(rw1, wcat);
  transpose_f2b_k<<<dim3(IDIM / 64, CDIM / 64, 8), 256, 0, stream>>>(ew1, ew1T, CDIM, IDIM);
  transpose_f2b_k<<<dim3(CDIM / 64, IDIM / 64, 8), 256, 0, stream>>>(ew2, ew2T, IDIM, CDIM);
  transpose_f2b_k<<<dim3(IDIM / 64, CDIM / 64, 1), 256, 0, stream>>>(sw1, sw1T, CDIM, IDIM);
  transpose_f2b_k<<<dim3(CDIM / 64, IDIM / 64, 1), 256, 0, stream>>>(sw2, sw2T, IDIM, CDIM);

  init_meta<<<PAIR_CAP / 256, 256, 0, stream>>>(meta, pair_token);

  // router hidden: rh slabs = x @ rw1 (+rb1 in slab 0); relu+sum in router_finish.
  // split-K=8 over RK=4096 -> 256 blocks, disjoint slabs (no atomics, no zeroing)
  gemm128<0, 0, true, 8><<<dim3(RHID / 128, TOK / 128, 8), 256, 0, stream>>>(
      xcat, wcat, nullptr, rb1, nullptr, rh, nullptr, nullptr, RHID, RK, TOK * RHID);
  router_finish<<<TOK / 4, 256, 0, stream>>>(rh, rw2, rb2, tok_e, tok_w, meta);
  compute_offsets<<<1, 64, 0, stream>>>(meta);
  scatter_pairs<<<TOK / 256, 256, 0, stream>>>(tok_e, meta, pair_token, pair_pos);

  // expert FFN (zz = 0..7 routed experts, zz = 8 shared expert over all tokens)
  gemm128<1, 2, false, 1><<<dim3(IDIM / 128, 16, 9), 256, 0, stream>>>(
      xb, ew1T, sw1T, eb1, sb1, h, meta, pair_token, IDIM, CDIM, 0);
  // GEMM2: split-K=2 over IDIM=4096 -> 2x blocks, disjoint slabs summed in combine
  gemm128<2, 0, true, 2><<<dim3(CDIM / 128, 16, 18), 256, 0, stream>>>(
      h, ew2T, sw2T, eb2, sb2, op, meta, nullptr, CDIM, IDIM, PAIR_CAP * CDIM);

  combine_out<<<TOK, 256, 0, stream>>>(op, pair_pos, tok_w, (float*)d_out);
}